// Round 10
// baseline (100.140 us; speedup 1.0000x reference)
//
#include <hip/hip_runtime.h>
#include <cmath>

#define BLOCK 1024  // 16 waves/block, 236 WGs total: proven r7 geometry
                    // (WG-cost law punishes workgroups; waves are cheap).
#define APT 2       // anchors per thread
#define CH 8        // k-chunk per staged buffer (2 buffers, double-buffered)

struct ArgmaxState {
    float bi[APT], bd[APT];
    int   bk[APT];
};

// Consume one staged CH-box buffer: argmax over iou = inter/(S - inter),
// S = aar + sar. x/(S-x) is monotone in x/S => candidate beats best
// <=> inter*bd > bi*S (cross-multiplied, exact operands, no divide).
// Strict > keeps the first max, matching the reference argmax.
__device__ __forceinline__ void consume_chunk(
    const float4* __restrict__ buf, int kbase,
    const float* ax, const float* ay, const float* axx, const float* ayy,
    const float* aar, ArgmaxState& st)
{
    #pragma unroll
    for (int j = 0; j < CH; ++j) {
        float4 g = buf[j];
        float sar = (g.z - g.x) * (g.w - g.y);  // bit-identical ref expr
        #pragma unroll
        for (int i = 0; i < APT; ++i) {
            float w = fminf(axx[i], g.z) - fmaxf(ax[i], g.x);
            float h = fminf(ayy[i], g.w) - fmaxf(ay[i], g.y);
            w = fmaxf(w, 0.f); h = fmaxf(h, 0.f);
            float inter = w * h;
            float S = aar[i] + sar;
            bool better = inter * st.bd[i] > st.bi[i] * S;
            st.bi[i] = better ? inter : st.bi[i];
            st.bd[i] = better ? S     : st.bd[i];
            st.bk[i] = better ? kbase + j : st.bk[i];
        }
    }
}

// part layout: per (b, gx) one float4 [pos_count, stc_sum, str_sum, pad],
// plain-stored by the owning block (no atomics, no zero-init, no memset
// node). Finalize kernel (stream-ordered) sums the slots.
__global__ void __launch_bounds__(BLOCK) ainno_main(
    const float* __restrict__ ss,       // (B, A, 6)
    const float* __restrict__ anchors,  // (A, 4) xywh
    const float* __restrict__ gt,       // (B, K, 4) xywh
    float* __restrict__ part,           // (B, gridDim.x, 4)
    int A, int K, int B)
{
    // K <= 64. GT boxes as xyxy staged once per block. Area recomputed from
    // the staged box (bit-identical expression): halves LDS issue count.
    __shared__ float4 gxy_s[64];
    __shared__ float  red[(BLOCK / 64) * 3];

    const int b    = blockIdx.y;
    const int tid  = threadIdx.x;
    const int lane = tid & 63;

    if (tid < K) {
        // Same arithmetic as reference: x2 = x + w.
        float4 g = ((const float4*)(gt + (size_t)b * K * 4))[tid];
        gxy_s[tid] = make_float4(g.x, g.y, g.x + g.z, g.y + g.w);
    }
    __syncthreads();

    const int tileSz = BLOCK * APT;                 // 2048
    const int ntiles = (A + tileSz - 1) / tileSz;   // 59 at A=120000

    float posf = 0.f, stcs = 0.f, strs = 0.f;

    // One tile per block at the default geometry (gridDim.x == ntiles).
    for (int tt = blockIdx.x; tt < ntiles; tt += gridDim.x) {
        const int base = tt * tileSz + tid;

        float ax[APT], ay[APT], axx[APT], ayy[APT], aar[APT];
        ArgmaxState st;
        #pragma unroll
        for (int i = 0; i < APT; ++i) {
            int a  = base + i * BLOCK;
            int ac = a < A ? a : A - 1;  // clamp; contribution guarded later
            float4 an = ((const float4*)anchors)[ac];
            ax[i]  = an.x;         ay[i]  = an.y;
            axx[i] = an.x + an.z;  ayy[i] = an.y + an.w;
            aar[i] = (axx[i] - ax[i]) * (ayy[i] - ay[i]);
            st.bi[i] = -1.f; st.bd[i] = 1.f; st.bk[i] = 0;
        }

        // Prefetch the logits: issued before the K-loop, consumed after, so
        // HBM/L2 latency hides under ~4k cycles of IoU math (r4-proven).
        const float* sp0 = ss + ((size_t)b * A + (base         < A ? base         : A - 1)) * 6;
        const float* sp1 = ss + ((size_t)b * A + (base + BLOCK < A ? base + BLOCK : A - 1)) * 6;
        float xlog0 = sp0[4];
        float xlog1 = sp1[4];

        // Hot loop: software-pipelined, double-buffered chunk staging with
        // statically-named buffers (rule #20: compile-time indices -> VGPR).
        // sched_barrier(0) pins each load batch before the compute that
        // hides it (r3/r7: compiler otherwise re-sinks staged loads into
        // per-k read->wait->use, exposing ~120cy LDS latency 64x/tile).
        if (K == 64) {
            float4 bufA[CH], bufB[CH];
            #pragma unroll
            for (int j = 0; j < CH; ++j) bufA[j] = gxy_s[j];
            #pragma unroll 1
            for (int k0 = 0; k0 < 64; k0 += 2 * CH) {
                #pragma unroll
                for (int j = 0; j < CH; ++j) bufB[j] = gxy_s[k0 + CH + j];
                __builtin_amdgcn_sched_barrier(0);
                consume_chunk(bufA, k0, ax, ay, axx, ayy, aar, st);
                if (k0 + 2 * CH < 64) {
                    #pragma unroll
                    for (int j = 0; j < CH; ++j) bufA[j] = gxy_s[k0 + 2 * CH + j];
                }
                __builtin_amdgcn_sched_barrier(0);
                consume_chunk(bufB, k0 + CH, ax, ay, axx, ayy, aar, st);
            }
        } else {
            // generic fallback (not taken for K=64)
            for (int k = 0; k < K; ++k) {
                float4 g = gxy_s[k];
                float sar = (g.z - g.x) * (g.w - g.y);
                #pragma unroll
                for (int i = 0; i < APT; ++i) {
                    float w = fminf(axx[i], g.z) - fmaxf(ax[i], g.x);
                    float h = fminf(ayy[i], g.w) - fmaxf(ay[i], g.y);
                    w = fmaxf(w, 0.f); h = fmaxf(h, 0.f);
                    float inter = w * h;
                    float S = aar[i] + sar;
                    bool better = inter * st.bd[i] > st.bi[i] * S;
                    st.bi[i] = better ? inter : st.bi[i];
                    st.bd[i] = better ? S     : st.bd[i];
                    st.bk[i] = better ? k     : st.bk[i];
                }
            }
        }

        #pragma unroll
        for (int i = 0; i < APT; ++i) {
            int a = base + i * BLOCK;
            // Winner box straight from LDS (divergent one-time gather);
            // its area recomputed with the identical expression.
            float4 wb  = gxy_s[st.bk[i]];
            float  war = (wb.z - wb.x) * (wb.w - wb.y);

            // score == ref max IoU bit-identically: bd-bi = (aar+sar)-inter,
            // same operand order as reference's (area_a + area_g) - inter.
            float score = st.bi[i] / (st.bd[i] - st.bi[i]);
            bool inb = a < A;
            bool pos = inb && (score >= 0.5f);
            bool neg = inb && (score < 0.4f);
            if (pos | neg) {
                const float* sp = (i == 0) ? sp0 : sp1;
                float x = (i == 0) ? xlog0 : xlog1;
                float e = expf(-x);
                float p = 1.f / (1.f + e);
                if (pos) {
                    posf += 1.f;
                    float ce  = log1pf(e);        // softplus(-x) = -log_sigmoid(x)
                    float omp = 1.f - p;
                    stcs += 0.25f * ce * omp * omp;

                    float px  = sp[0], py = sp[1];
                    float pxx = px + sp[2], pyy = py + sp[3];
                    float ew = fminf(pxx, wb.z) - fmaxf(px, wb.x);
                    float eh = fminf(pyy, wb.w) - fmaxf(py, wb.y);
                    ew = fmaxf(ew, 0.f); eh = fmaxf(eh, 0.f);
                    float einter = ew * eh;
                    float pa = (pxx - px) * (pyy - py);
                    float eiou = einter / (pa + war - einter);
                    strs += -logf(eiou + 0.01f);
                } else {
                    float ce = log1pf(expf(x));   // softplus(x) = -log_sigmoid(-x)
                    stcs += 0.75f * ce * p * p;
                }
            }
        }
    }

    // wave64 shuffle reduction -> LDS across waves -> one plain float4 store
    float v0 = posf, v1 = stcs, v2 = strs;
    for (int off = 32; off > 0; off >>= 1) {
        v0 += __shfl_down(v0, off, 64);
        v1 += __shfl_down(v1, off, 64);
        v2 += __shfl_down(v2, off, 64);
    }
    const int wave = tid >> 6;
    if (lane == 0) {
        red[wave * 3 + 0] = v0;
        red[wave * 3 + 1] = v1;
        red[wave * 3 + 2] = v2;
    }
    __syncthreads();
    if (tid == 0) {
        float s0 = 0.f, s1 = 0.f, s2 = 0.f;
        for (int w = 0; w < BLOCK / 64; ++w) {
            s0 += red[w * 3 + 0];
            s1 += red[w * 3 + 1];
            s2 += red[w * 3 + 2];
        }
        // Own slot, plain store: no atomics, no pre-zeroed memory needed.
        ((float4*)part)[(size_t)b * gridDim.x + blockIdx.x] =
            make_float4(s0, s1, s2, 0.f);
    }
}

// Finalize: stream ordering guarantees visibility of main's stores.
// Sums the (B x GX) partial slots and applies the per-batch normalization.
__global__ void ainno_final(const float* __restrict__ part,
                            float* __restrict__ out, int GX, int B)
{
    __shared__ float tot_s[4];
    const int tid = threadIdx.x, lane = tid & 63, wave = tid >> 6; // 4 waves
    float t = 0.f;
    for (int bb = wave; bb < B; bb += 4) {
        float pc = 0.f, st = 0.f, sr = 0.f;
        for (int i = lane; i < GX; i += 64) {
            const float* p = part + ((size_t)bb * GX + i) * 4;
            pc += p[0]; st += p[1]; sr += p[2];
        }
        for (int off = 32; off > 0; off >>= 1) {
            pc += __shfl_down(pc, off, 64);
            st += __shfl_down(st, off, 64);
            sr += __shfl_down(sr, off, 64);
        }
        if (lane == 0) {
            float safe = pc > 0.f ? pc : 1.f;
            float v = st / safe;
            if (pc > 0.f) v += sr / safe;
            t += v;
        }
    }
    if (lane == 0) tot_s[wave] = t;
    __syncthreads();
    if (tid == 0) {
        float s = 0.f;
        for (int w = 0; w < 4; ++w) s += tot_s[w];
        out[0] = s / (float)B;
    }
}

extern "C" void kernel_launch(void* const* d_in, const int* in_sizes, int n_in,
                              void* d_out, int out_size, void* d_ws, size_t ws_size,
                              hipStream_t stream) {
    const float* ss      = (const float*)d_in[0];
    const float* anchors = (const float*)d_in[1];
    const float* gt      = (const float*)d_in[2];
    float* out  = (float*)d_out;
    float* part = (float*)d_ws;

    const int A = in_sizes[1] / 4;
    const int B = in_sizes[0] / (A * 6);
    const int K = in_sizes[2] / (B * 4);

    const int tileSz = BLOCK * APT;                  // 2048
    const int ntiles = (A + tileSz - 1) / tileSz;    // 59 at A=120000
    const int gx     = ntiles;                       // 236 WGs total

    dim3 grid(gx, B);
    ainno_main<<<grid, BLOCK, 0, stream>>>(ss, anchors, gt, part, A, K, B);
    ainno_final<<<dim3(1), 256, 0, stream>>>(part, out, gx, B);
}

// Round 11
// 98.624 us; speedup vs baseline: 1.0154x; 1.0154x over previous
//
#include <hip/hip_runtime.h>
#include <cmath>

#define BLOCK 1024  // 16 waves/block, 236 WGs total: proven r7 geometry
                    // (WG-cost law punishes workgroups; waves are cheap).
#define APT 2       // anchors per thread
#define CH 8        // k-chunk per staged buffer (2 buffers, double-buffered)

struct ArgmaxState {
    float bi[APT], bd[APT];
    int   bk[APT];
};

// Consume one staged CH-box buffer: argmax over iou = inter/(S - inter),
// S = aar + sar. x/(S-x) is monotone in x/S => candidate beats best
// <=> inter*bd > bi*S (cross-multiplied, exact operands, no divide).
// Strict > keeps the first max, matching the reference argmax.
__device__ __forceinline__ void consume_chunk(
    const float4* __restrict__ buf, int kbase,
    const float* ax, const float* ay, const float* axx, const float* ayy,
    const float* aar, ArgmaxState& st)
{
    #pragma unroll
    for (int j = 0; j < CH; ++j) {
        float4 g = buf[j];
        float sar = (g.z - g.x) * (g.w - g.y);  // bit-identical ref expr
        #pragma unroll
        for (int i = 0; i < APT; ++i) {
            float w = fminf(axx[i], g.z) - fmaxf(ax[i], g.x);
            float h = fminf(ayy[i], g.w) - fmaxf(ay[i], g.y);
            w = fmaxf(w, 0.f); h = fmaxf(h, 0.f);
            float inter = w * h;
            float S = aar[i] + sar;
            bool better = inter * st.bd[i] > st.bi[i] * S;
            st.bi[i] = better ? inter : st.bi[i];
            st.bd[i] = better ? S     : st.bd[i];
            st.bk[i] = better ? kbase + j : st.bk[i];
        }
    }
}

// part layout: per (b, gx) one float4 [pos_count, stc_sum, str_sum, pad],
// plain-stored by the owning block (no atomics, no zero-init, no memset
// node). Finalize kernel (stream-ordered) sums the slots.
//
// __launch_bounds__(1024, 4): min 4 waves/EU = 16 waves/CU = exactly 1 WG/CU
// -> VGPR cap 128 (r10's default cap of 64 scratch-spilled the two CH=8
// float4 staging buffers: WRITE_SIZE 51 MB, FETCH +23 MB). Our 236-WG
// geometry never gets >1 WG/CU anyway, so this costs zero real occupancy.
__global__ void __launch_bounds__(BLOCK, 4) ainno_main(
    const float* __restrict__ ss,       // (B, A, 6)
    const float* __restrict__ anchors,  // (A, 4) xywh
    const float* __restrict__ gt,       // (B, K, 4) xywh
    float* __restrict__ part,           // (B, gridDim.x, 4)
    int A, int K, int B)
{
    // K <= 64. GT boxes as xyxy staged once per block. Area recomputed from
    // the staged box (bit-identical expression): halves LDS issue count.
    __shared__ float4 gxy_s[64];
    __shared__ float  red[(BLOCK / 64) * 3];

    const int b    = blockIdx.y;
    const int tid  = threadIdx.x;
    const int lane = tid & 63;

    if (tid < K) {
        // Same arithmetic as reference: x2 = x + w.
        float4 g = ((const float4*)(gt + (size_t)b * K * 4))[tid];
        gxy_s[tid] = make_float4(g.x, g.y, g.x + g.z, g.y + g.w);
    }
    __syncthreads();

    const int tileSz = BLOCK * APT;                 // 2048
    const int ntiles = (A + tileSz - 1) / tileSz;   // 59 at A=120000

    float posf = 0.f, stcs = 0.f, strs = 0.f;

    // One tile per block at the default geometry (gridDim.x == ntiles).
    for (int tt = blockIdx.x; tt < ntiles; tt += gridDim.x) {
        const int base = tt * tileSz + tid;

        float ax[APT], ay[APT], axx[APT], ayy[APT], aar[APT];
        ArgmaxState st;
        #pragma unroll
        for (int i = 0; i < APT; ++i) {
            int a  = base + i * BLOCK;
            int ac = a < A ? a : A - 1;  // clamp; contribution guarded later
            float4 an = ((const float4*)anchors)[ac];
            ax[i]  = an.x;         ay[i]  = an.y;
            axx[i] = an.x + an.z;  ayy[i] = an.y + an.w;
            aar[i] = (axx[i] - ax[i]) * (ayy[i] - ay[i]);
            st.bi[i] = -1.f; st.bd[i] = 1.f; st.bk[i] = 0;
        }

        // Prefetch the logits: issued before the K-loop, consumed after, so
        // HBM/L2 latency hides under ~4k cycles of IoU math (r4-proven).
        const float* sp0 = ss + ((size_t)b * A + (base         < A ? base         : A - 1)) * 6;
        const float* sp1 = ss + ((size_t)b * A + (base + BLOCK < A ? base + BLOCK : A - 1)) * 6;
        float xlog0 = sp0[4];
        float xlog1 = sp1[4];

        // Hot loop: software-pipelined, double-buffered chunk staging with
        // statically-named buffers (rule #20: compile-time indices -> VGPR).
        // sched_barrier(0) pins each load batch before the compute that
        // hides it (r3/r7: compiler otherwise re-sinks staged loads into
        // per-k read->wait->use, exposing ~120cy LDS latency 64x/tile).
        if (K == 64) {
            float4 bufA[CH], bufB[CH];
            #pragma unroll
            for (int j = 0; j < CH; ++j) bufA[j] = gxy_s[j];
            #pragma unroll 1
            for (int k0 = 0; k0 < 64; k0 += 2 * CH) {
                #pragma unroll
                for (int j = 0; j < CH; ++j) bufB[j] = gxy_s[k0 + CH + j];
                __builtin_amdgcn_sched_barrier(0);
                consume_chunk(bufA, k0, ax, ay, axx, ayy, aar, st);
                if (k0 + 2 * CH < 64) {
                    #pragma unroll
                    for (int j = 0; j < CH; ++j) bufA[j] = gxy_s[k0 + 2 * CH + j];
                }
                __builtin_amdgcn_sched_barrier(0);
                consume_chunk(bufB, k0 + CH, ax, ay, axx, ayy, aar, st);
            }
        } else {
            // generic fallback (not taken for K=64)
            for (int k = 0; k < K; ++k) {
                float4 g = gxy_s[k];
                float sar = (g.z - g.x) * (g.w - g.y);
                #pragma unroll
                for (int i = 0; i < APT; ++i) {
                    float w = fminf(axx[i], g.z) - fmaxf(ax[i], g.x);
                    float h = fminf(ayy[i], g.w) - fmaxf(ay[i], g.y);
                    w = fmaxf(w, 0.f); h = fmaxf(h, 0.f);
                    float inter = w * h;
                    float S = aar[i] + sar;
                    bool better = inter * st.bd[i] > st.bi[i] * S;
                    st.bi[i] = better ? inter : st.bi[i];
                    st.bd[i] = better ? S     : st.bd[i];
                    st.bk[i] = better ? k     : st.bk[i];
                }
            }
        }

        #pragma unroll
        for (int i = 0; i < APT; ++i) {
            int a = base + i * BLOCK;
            // Winner box straight from LDS (divergent one-time gather);
            // its area recomputed with the identical expression.
            float4 wb  = gxy_s[st.bk[i]];
            float  war = (wb.z - wb.x) * (wb.w - wb.y);

            // score == ref max IoU bit-identically: bd-bi = (aar+sar)-inter,
            // same operand order as reference's (area_a + area_g) - inter.
            float score = st.bi[i] / (st.bd[i] - st.bi[i]);
            bool inb = a < A;
            bool pos = inb && (score >= 0.5f);
            bool neg = inb && (score < 0.4f);
            if (pos | neg) {
                const float* sp = (i == 0) ? sp0 : sp1;
                float x = (i == 0) ? xlog0 : xlog1;
                float e = expf(-x);
                float p = 1.f / (1.f + e);
                if (pos) {
                    posf += 1.f;
                    float ce  = log1pf(e);        // softplus(-x) = -log_sigmoid(x)
                    float omp = 1.f - p;
                    stcs += 0.25f * ce * omp * omp;

                    float px  = sp[0], py = sp[1];
                    float pxx = px + sp[2], pyy = py + sp[3];
                    float ew = fminf(pxx, wb.z) - fmaxf(px, wb.x);
                    float eh = fminf(pyy, wb.w) - fmaxf(py, wb.y);
                    ew = fmaxf(ew, 0.f); eh = fmaxf(eh, 0.f);
                    float einter = ew * eh;
                    float pa = (pxx - px) * (pyy - py);
                    float eiou = einter / (pa + war - einter);
                    strs += -logf(eiou + 0.01f);
                } else {
                    float ce = log1pf(expf(x));   // softplus(x) = -log_sigmoid(-x)
                    stcs += 0.75f * ce * p * p;
                }
            }
        }
    }

    // wave64 shuffle reduction -> LDS across waves -> one plain float4 store
    float v0 = posf, v1 = stcs, v2 = strs;
    for (int off = 32; off > 0; off >>= 1) {
        v0 += __shfl_down(v0, off, 64);
        v1 += __shfl_down(v1, off, 64);
        v2 += __shfl_down(v2, off, 64);
    }
    const int wave = tid >> 6;
    if (lane == 0) {
        red[wave * 3 + 0] = v0;
        red[wave * 3 + 1] = v1;
        red[wave * 3 + 2] = v2;
    }
    __syncthreads();
    if (tid == 0) {
        float s0 = 0.f, s1 = 0.f, s2 = 0.f;
        for (int w = 0; w < BLOCK / 64; ++w) {
            s0 += red[w * 3 + 0];
            s1 += red[w * 3 + 1];
            s2 += red[w * 3 + 2];
        }
        // Own slot, plain store: no atomics, no pre-zeroed memory needed.
        ((float4*)part)[(size_t)b * gridDim.x + blockIdx.x] =
            make_float4(s0, s1, s2, 0.f);
    }
}

// Finalize: stream ordering guarantees visibility of main's stores.
// Sums the (B x GX) partial slots and applies the per-batch normalization.
__global__ void ainno_final(const float* __restrict__ part,
                            float* __restrict__ out, int GX, int B)
{
    __shared__ float tot_s[4];
    const int tid = threadIdx.x, lane = tid & 63, wave = tid >> 6; // 4 waves
    float t = 0.f;
    for (int bb = wave; bb < B; bb += 4) {
        float pc = 0.f, st = 0.f, sr = 0.f;
        for (int i = lane; i < GX; i += 64) {
            const float* p = part + ((size_t)bb * GX + i) * 4;
            pc += p[0]; st += p[1]; sr += p[2];
        }
        for (int off = 32; off > 0; off >>= 1) {
            pc += __shfl_down(pc, off, 64);
            st += __shfl_down(st, off, 64);
            sr += __shfl_down(sr, off, 64);
        }
        if (lane == 0) {
            float safe = pc > 0.f ? pc : 1.f;
            float v = st / safe;
            if (pc > 0.f) v += sr / safe;
            t += v;
        }
    }
    if (lane == 0) tot_s[wave] = t;
    __syncthreads();
    if (tid == 0) {
        float s = 0.f;
        for (int w = 0; w < 4; ++w) s += tot_s[w];
        out[0] = s / (float)B;
    }
}

extern "C" void kernel_launch(void* const* d_in, const int* in_sizes, int n_in,
                              void* d_out, int out_size, void* d_ws, size_t ws_size,
                              hipStream_t stream) {
    const float* ss      = (const float*)d_in[0];
    const float* anchors = (const float*)d_in[1];
    const float* gt      = (const float*)d_in[2];
    float* out  = (float*)d_out;
    float* part = (float*)d_ws;

    const int A = in_sizes[1] / 4;
    const int B = in_sizes[0] / (A * 6);
    const int K = in_sizes[2] / (B * 4);

    const int tileSz = BLOCK * APT;                  // 2048
    const int ntiles = (A + tileSz - 1) / tileSz;    // 59 at A=120000
    const int gx     = ntiles;                       // 236 WGs total

    dim3 grid(gx, B);
    ainno_main<<<grid, BLOCK, 0, stream>>>(ss, anchors, gt, part, A, K, B);
    ainno_final<<<dim3(1), 256, 0, stream>>>(part, out, gx, B);
}

// Round 12
// 86.548 us; speedup vs baseline: 1.1570x; 1.1395x over previous
//
#include <hip/hip_runtime.h>
#include <cmath>

#define BLOCK 1024  // 16 waves/block, 236 WGs total: proven r7 geometry
                    // (WG-cost law punishes workgroups; waves are cheap).
#define APT 2       // anchors per thread

// part layout: per (b, gx) one float4 [pos_count, stc_sum, str_sum, pad],
// plain-stored by the owning block (no atomics, no zero-init, no memset
// node). Finalize kernel (stream-ordered) sums the slots.
//
// amdgpu_waves_per_eu(4,4): exactly 4 waves/EU (= the 16 waves of one
// 1024-thread block on 4 SIMDs) -> VGPR budget 128. r10/r11 showed
// __launch_bounds__' 2nd arg did NOT raise the 64-VGPR cap and the staged
// chunks spilled (WRITE_SIZE 49-51 MB). This attribute talks to RA directly.
__global__ void __launch_bounds__(BLOCK)
__attribute__((amdgpu_waves_per_eu(4, 4)))
ainno_main(
    const float* __restrict__ ss,       // (B, A, 6)
    const float* __restrict__ anchors,  // (A, 4) xywh
    const float* __restrict__ gt,       // (B, K, 4) xywh
    float* __restrict__ part,           // (B, gridDim.x, 4)
    int A, int K, int B)
{
    // K <= 64. GT boxes as xyxy staged once per block. Area recomputed from
    // the staged box (bit-identical reference expression).
    __shared__ float4 gxy_s[64];
    __shared__ float  red[(BLOCK / 64) * 3];

    const int b    = blockIdx.y;
    const int tid  = threadIdx.x;
    const int lane = tid & 63;

    if (tid < K) {
        // Same arithmetic as reference: x2 = x + w.
        float4 g = ((const float4*)(gt + (size_t)b * K * 4))[tid];
        gxy_s[tid] = make_float4(g.x, g.y, g.x + g.z, g.y + g.w);
    }
    __syncthreads();

    const int tileSz = BLOCK * APT;                 // 2048
    const int ntiles = (A + tileSz - 1) / tileSz;   // 59 at A=120000

    float posf = 0.f, stcs = 0.f, strs = 0.f;

// Consume ONE staged box (named float4, never an array -> never scratch).
// Argmax over iou = inter/(S - inter), S = aar + sar: x/(S-x) is monotone
// in x/S => candidate beats best <=> inter*bd > bi*S (cross-multiplied,
// exact operands, no divide). Strict > keeps the first max (ref argmax).
#define CONSUME(g, kk)                                              \
    {                                                               \
        float sar = ((g).z - (g).x) * ((g).w - (g).y);              \
        _Pragma("unroll")                                           \
        for (int i = 0; i < APT; ++i) {                             \
            float w = fminf(axx[i], (g).z) - fmaxf(ax[i], (g).x);   \
            float h = fminf(ayy[i], (g).w) - fmaxf(ay[i], (g).y);   \
            w = fmaxf(w, 0.f); h = fmaxf(h, 0.f);                   \
            float inter = w * h;                                    \
            float S = aar[i] + sar;                                 \
            bool better = inter * bd[i] > bi[i] * S;                \
            bi[i] = better ? inter : bi[i];                         \
            bd[i] = better ? S : bd[i];                             \
            bk[i] = better ? (kk) : bk[i];                          \
        }                                                           \
    }

    // One tile per block at the default geometry (gridDim.x == ntiles).
    for (int tt = blockIdx.x; tt < ntiles; tt += gridDim.x) {
        const int base = tt * tileSz + tid;

        float ax[APT], ay[APT], axx[APT], ayy[APT], aar[APT];
        float bi[APT], bd[APT];
        int   bk[APT];
        #pragma unroll
        for (int i = 0; i < APT; ++i) {
            int a  = base + i * BLOCK;
            int ac = a < A ? a : A - 1;  // clamp; contribution guarded later
            float4 an = ((const float4*)anchors)[ac];
            ax[i]  = an.x;         ay[i]  = an.y;
            axx[i] = an.x + an.z;  ayy[i] = an.y + an.w;
            aar[i] = (axx[i] - ax[i]) * (ayy[i] - ay[i]);
            bi[i] = -1.f; bd[i] = 1.f; bk[i] = 0;
        }

        // Prefetch the logits: issued before the K-loop, consumed after, so
        // HBM/L2 latency hides under ~4k cycles of IoU math (r4-proven).
        const float* sp0 = ss + ((size_t)b * A + (base         < A ? base         : A - 1)) * 6;
        const float* sp1 = ss + ((size_t)b * A + (base + BLOCK < A ? base + BLOCK : A - 1)) * 6;
        float xlog0 = sp0[4];
        float xlog1 = sp1[4];

        // Hot loop: double-buffered 4-box chunks in NAMED registers.
        // sched_barrier(0) fences pin each load batch above the compute
        // that hides it (r3: compiler re-sinks into per-k read->wait->use;
        // r10/r11: arrays through a function arg went to scratch). First
        // use of a batch is 1 chunk later -> one lgkmcnt wait per 4 boxes,
        // covered by ~256 issue-cycles of the other buffer's compute.
        if (K == 64) {
            float4 a0 = gxy_s[0], a1 = gxy_s[1], a2 = gxy_s[2], a3 = gxy_s[3];
            #pragma unroll 1
            for (int k0 = 0; k0 < 64; k0 += 8) {
                float4 b0 = gxy_s[k0 + 4], b1 = gxy_s[k0 + 5],
                       b2 = gxy_s[k0 + 6], b3 = gxy_s[k0 + 7];
                __builtin_amdgcn_sched_barrier(0);
                CONSUME(a0, k0 + 0) CONSUME(a1, k0 + 1)
                CONSUME(a2, k0 + 2) CONSUME(a3, k0 + 3)
                if (k0 + 8 < 64) {
                    a0 = gxy_s[k0 + 8];  a1 = gxy_s[k0 + 9];
                    a2 = gxy_s[k0 + 10]; a3 = gxy_s[k0 + 11];
                }
                __builtin_amdgcn_sched_barrier(0);
                CONSUME(b0, k0 + 4) CONSUME(b1, k0 + 5)
                CONSUME(b2, k0 + 6) CONSUME(b3, k0 + 7)
            }
        } else {
            // generic fallback (not taken for K=64)
            for (int k = 0; k < K; ++k) {
                float4 g = gxy_s[k];
                CONSUME(g, k)
            }
        }

        #pragma unroll
        for (int i = 0; i < APT; ++i) {
            int a = base + i * BLOCK;
            // Winner box straight from LDS (divergent one-time gather);
            // its area recomputed with the identical expression.
            float4 wb  = gxy_s[bk[i]];
            float  war = (wb.z - wb.x) * (wb.w - wb.y);

            // score == ref max IoU bit-identically: bd-bi = (aar+sar)-inter,
            // same operand order as reference's (area_a + area_g) - inter.
            float score = bi[i] / (bd[i] - bi[i]);
            bool inb = a < A;
            bool pos = inb && (score >= 0.5f);
            bool neg = inb && (score < 0.4f);
            if (pos | neg) {
                const float* sp = (i == 0) ? sp0 : sp1;
                float x = (i == 0) ? xlog0 : xlog1;
                float e = expf(-x);
                float p = 1.f / (1.f + e);
                if (pos) {
                    posf += 1.f;
                    float ce  = log1pf(e);        // softplus(-x) = -log_sigmoid(x)
                    float omp = 1.f - p;
                    stcs += 0.25f * ce * omp * omp;

                    float px  = sp[0], py = sp[1];
                    float pxx = px + sp[2], pyy = py + sp[3];
                    float ew = fminf(pxx, wb.z) - fmaxf(px, wb.x);
                    float eh = fminf(pyy, wb.w) - fmaxf(py, wb.y);
                    ew = fmaxf(ew, 0.f); eh = fmaxf(eh, 0.f);
                    float einter = ew * eh;
                    float pa = (pxx - px) * (pyy - py);
                    float eiou = einter / (pa + war - einter);
                    strs += -logf(eiou + 0.01f);
                } else {
                    float ce = log1pf(expf(x));   // softplus(x) = -log_sigmoid(-x)
                    stcs += 0.75f * ce * p * p;
                }
            }
        }
    }
#undef CONSUME

    // wave64 shuffle reduction -> LDS across waves -> one plain float4 store
    float v0 = posf, v1 = stcs, v2 = strs;
    for (int off = 32; off > 0; off >>= 1) {
        v0 += __shfl_down(v0, off, 64);
        v1 += __shfl_down(v1, off, 64);
        v2 += __shfl_down(v2, off, 64);
    }
    const int wave = tid >> 6;
    if (lane == 0) {
        red[wave * 3 + 0] = v0;
        red[wave * 3 + 1] = v1;
        red[wave * 3 + 2] = v2;
    }
    __syncthreads();
    if (tid == 0) {
        float s0 = 0.f, s1 = 0.f, s2 = 0.f;
        for (int w = 0; w < BLOCK / 64; ++w) {
            s0 += red[w * 3 + 0];
            s1 += red[w * 3 + 1];
            s2 += red[w * 3 + 2];
        }
        // Own slot, plain store: no atomics, no pre-zeroed memory needed.
        ((float4*)part)[(size_t)b * gridDim.x + blockIdx.x] =
            make_float4(s0, s1, s2, 0.f);
    }
}

// Finalize: stream ordering guarantees visibility of main's stores.
// Sums the (B x GX) partial slots and applies the per-batch normalization.
__global__ void ainno_final(const float* __restrict__ part,
                            float* __restrict__ out, int GX, int B)
{
    __shared__ float tot_s[4];
    const int tid = threadIdx.x, lane = tid & 63, wave = tid >> 6; // 4 waves
    float t = 0.f;
    for (int bb = wave; bb < B; bb += 4) {
        float pc = 0.f, st = 0.f, sr = 0.f;
        for (int i = lane; i < GX; i += 64) {
            const float* p = part + ((size_t)bb * GX + i) * 4;
            pc += p[0]; st += p[1]; sr += p[2];
        }
        for (int off = 32; off > 0; off >>= 1) {
            pc += __shfl_down(pc, off, 64);
            st += __shfl_down(st, off, 64);
            sr += __shfl_down(sr, off, 64);
        }
        if (lane == 0) {
            float safe = pc > 0.f ? pc : 1.f;
            float v = st / safe;
            if (pc > 0.f) v += sr / safe;
            t += v;
        }
    }
    if (lane == 0) tot_s[wave] = t;
    __syncthreads();
    if (tid == 0) {
        float s = 0.f;
        for (int w = 0; w < 4; ++w) s += tot_s[w];
        out[0] = s / (float)B;
    }
}

extern "C" void kernel_launch(void* const* d_in, const int* in_sizes, int n_in,
                              void* d_out, int out_size, void* d_ws, size_t ws_size,
                              hipStream_t stream) {
    const float* ss      = (const float*)d_in[0];
    const float* anchors = (const float*)d_in[1];
    const float* gt      = (const float*)d_in[2];
    float* out  = (float*)d_out;
    float* part = (float*)d_ws;

    const int A = in_sizes[1] / 4;
    const int B = in_sizes[0] / (A * 6);
    const int K = in_sizes[2] / (B * 4);

    const int tileSz = BLOCK * APT;                  // 2048
    const int ntiles = (A + tileSz - 1) / tileSz;    // 59 at A=120000
    const int gx     = ntiles;                       // 236 WGs total

    dim3 grid(gx, B);
    ainno_main<<<grid, BLOCK, 0, stream>>>(ss, anchors, gt, part, A, K, B);
    ainno_final<<<dim3(1), 256, 0, stream>>>(part, out, gx, B);
}

// Round 13
// 84.943 us; speedup vs baseline: 1.1789x; 1.0189x over previous
//
#include <hip/hip_runtime.h>
#include <cmath>

#define BLOCK 1024  // 16 waves/block, 236 WGs total: proven r7 geometry
                    // (WG-cost law punishes workgroups; waves are cheap).
#define APT 2       // anchors per thread (proven r2/r3/r6 inner loop)
#define CH 8        // k-chunk staged per group (runtime chunk idx prevents
                    // r5-style whole-loop hoist/spill; VGPR stayed ~32)

// part layout: per (b, gx) one float4 [pos_count, stc_sum, str_sum, pad],
// plain-stored by the owning block (no atomics, no zero-init, no memset
// node). Finalize kernel (stream-ordered) sums the slots.
__global__ void __launch_bounds__(BLOCK) ainno_main(
    const float* __restrict__ ss,       // (B, A, 6)
    const float* __restrict__ anchors,  // (A, 4) xywh
    const float* __restrict__ gt,       // (B, K, 4) xywh
    float* __restrict__ part,           // (B, gridDim.x, 4)
    int A, int K, int B)
{
    // K <= 64. Derived GT boxes staged once per block.
    __shared__ float4 gxy_s[64];
    __shared__ float  gar_s[64];
    __shared__ float  red[(BLOCK / 64) * 3];

    const int b    = blockIdx.y;
    const int tid  = threadIdx.x;
    const int lane = tid & 63;

    if (tid < K) {
        // Same arithmetic as reference: x2 = x + w, area = (x2-x)*(y2-y).
        float4 g = ((const float4*)(gt + (size_t)b * K * 4))[tid];
        float x2 = g.x + g.z, y2 = g.y + g.w;
        gxy_s[tid] = make_float4(g.x, g.y, x2, y2);
        gar_s[tid] = (x2 - g.x) * (y2 - g.y);
    }
    __syncthreads();

    const int tileSz = BLOCK * APT;                 // 2048
    const int ntiles = (A + tileSz - 1) / tileSz;   // 59 at A=120000

    float posf = 0.f, stcs = 0.f, strs = 0.f;

    // One tile per block at the default geometry (gridDim.x == ntiles);
    // loop kept for generality/robustness.
    for (int tt = blockIdx.x; tt < ntiles; tt += gridDim.x) {
        const int base = tt * tileSz + tid;

        float ax[APT], ay[APT], axx[APT], ayy[APT], aar[APT];
        float bi[APT], bd[APT];
        int   bk[APT];
        #pragma unroll
        for (int i = 0; i < APT; ++i) {
            int a  = base + i * BLOCK;
            int ac = a < A ? a : A - 1;  // clamp; contribution guarded later
            float4 an = ((const float4*)anchors)[ac];
            ax[i]  = an.x;         ay[i]  = an.y;
            axx[i] = an.x + an.z;  ayy[i] = an.y + an.w;
            aar[i] = (axx[i] - ax[i]) * (ayy[i] - ay[i]);
            bi[i] = -1.f; bd[i] = 1.f; bk[i] = 0;
        }

        // Hot loop: EXACT r2/r3/r6 structure (proven codegen, no spill).
        // Argmax over iou = inter/(S - inter), S = aar + sar: x/(S-x) is
        // monotone in x/S => candidate beats best <=> inter*bd > bi*S
        // (cross-multiplied, exact operands, no divide). Strict > keeps
        // the first max, matching the reference argmax.
        const int kfull = K & ~(CH - 1);
        for (int k0 = 0; k0 < kfull; k0 += CH) {
            float4 gg[CH];
            float  sar[CH];
            #pragma unroll
            for (int j = 0; j < CH; ++j) {
                gg[j]  = gxy_s[k0 + j];  // ds_read_b128, uniform -> broadcast
                sar[j] = gar_s[k0 + j];  // ds_read_b32
            }
            #pragma unroll
            for (int j = 0; j < CH; ++j) {
                #pragma unroll
                for (int i = 0; i < APT; ++i) {
                    float w = fminf(axx[i], gg[j].z) - fmaxf(ax[i], gg[j].x);
                    float h = fminf(ayy[i], gg[j].w) - fmaxf(ay[i], gg[j].y);
                    w = fmaxf(w, 0.f); h = fmaxf(h, 0.f);
                    float inter = w * h;
                    float S = aar[i] + sar[j];
                    bool better = inter * bd[i] > bi[i] * S;
                    bi[i] = better ? inter : bi[i];
                    bd[i] = better ? S     : bd[i];
                    bk[i] = better ? (k0 + j) : bk[i];
                }
            }
        }
        for (int k = kfull; k < K; ++k) {   // tail (not taken for K=64)
            float4 gg  = gxy_s[k];
            float  sar = gar_s[k];
            #pragma unroll
            for (int i = 0; i < APT; ++i) {
                float w = fminf(axx[i], gg.z) - fmaxf(ax[i], gg.x);
                float h = fminf(ayy[i], gg.w) - fmaxf(ay[i], gg.y);
                w = fmaxf(w, 0.f); h = fmaxf(h, 0.f);
                float inter = w * h;
                float S = aar[i] + sar;
                bool better = inter * bd[i] > bi[i] * S;
                bi[i] = better ? inter : bi[i];
                bd[i] = better ? S     : bd[i];
                bk[i] = better ? k     : bk[i];
            }
        }

        #pragma unroll
        for (int i = 0; i < APT; ++i) {
            int a = base + i * BLOCK;
            // Winner box straight from LDS (divergent one-time gather).
            float4 wb  = gxy_s[bk[i]];
            float  war = gar_s[bk[i]];

            // score == ref max IoU bit-identically: bd-bi = (aar+sar)-inter,
            // same operand order as reference's (area_a + area_g) - inter.
            float score = bi[i] / (bd[i] - bi[i]);
            bool inb = a < A;
            bool pos = inb && (score >= 0.5f);
            bool neg = inb && (score < 0.4f);
            if (pos | neg) {
                const float* sp = ss + ((size_t)b * A + a) * 6;
                float x = sp[4];
                float e = expf(-x);
                float p = 1.f / (1.f + e);
                if (pos) {
                    posf += 1.f;
                    float ce  = log1pf(e);        // softplus(-x) = -log_sigmoid(x)
                    float omp = 1.f - p;
                    stcs += 0.25f * ce * omp * omp;

                    float px  = sp[0], py = sp[1];
                    float pxx = px + sp[2], pyy = py + sp[3];
                    float ew = fminf(pxx, wb.z) - fmaxf(px, wb.x);
                    float eh = fminf(pyy, wb.w) - fmaxf(py, wb.y);
                    ew = fmaxf(ew, 0.f); eh = fmaxf(eh, 0.f);
                    float einter = ew * eh;
                    float pa = (pxx - px) * (pyy - py);
                    float eiou = einter / (pa + war - einter);
                    strs += -logf(eiou + 0.01f);
                } else {
                    float ce = log1pf(expf(x));   // softplus(x) = -log_sigmoid(-x)
                    stcs += 0.75f * ce * p * p;
                }
            }
        }
    }

    // wave64 shuffle reduction -> LDS across waves -> one plain float4 store
    float v0 = posf, v1 = stcs, v2 = strs;
    for (int off = 32; off > 0; off >>= 1) {
        v0 += __shfl_down(v0, off, 64);
        v1 += __shfl_down(v1, off, 64);
        v2 += __shfl_down(v2, off, 64);
    }
    const int wave = tid >> 6;
    if (lane == 0) {
        red[wave * 3 + 0] = v0;
        red[wave * 3 + 1] = v1;
        red[wave * 3 + 2] = v2;
    }
    __syncthreads();
    if (tid == 0) {
        float s0 = 0.f, s1 = 0.f, s2 = 0.f;
        for (int w = 0; w < BLOCK / 64; ++w) {
            s0 += red[w * 3 + 0];
            s1 += red[w * 3 + 1];
            s2 += red[w * 3 + 2];
        }
        // Own slot, plain store: no atomics, no pre-zeroed memory needed.
        ((float4*)part)[(size_t)b * gridDim.x + blockIdx.x] =
            make_float4(s0, s1, s2, 0.f);
    }
}

// Finalize: stream ordering guarantees visibility of main's stores.
// Sums the (B x GX) partial slots and applies the per-batch normalization.
__global__ void ainno_final(const float* __restrict__ part,
                            float* __restrict__ out, int GX, int B)
{
    __shared__ float tot_s[4];
    const int tid = threadIdx.x, lane = tid & 63, wave = tid >> 6; // 4 waves
    float t = 0.f;
    for (int bb = wave; bb < B; bb += 4) {
        float pc = 0.f, st = 0.f, sr = 0.f;
        for (int i = lane; i < GX; i += 64) {
            const float* p = part + ((size_t)bb * GX + i) * 4;
            pc += p[0]; st += p[1]; sr += p[2];
        }
        for (int off = 32; off > 0; off >>= 1) {
            pc += __shfl_down(pc, off, 64);
            st += __shfl_down(st, off, 64);
            sr += __shfl_down(sr, off, 64);
        }
        if (lane == 0) {
            float safe = pc > 0.f ? pc : 1.f;
            float v = st / safe;
            if (pc > 0.f) v += sr / safe;
            t += v;
        }
    }
    if (lane == 0) tot_s[wave] = t;
    __syncthreads();
    if (tid == 0) {
        float s = 0.f;
        for (int w = 0; w < 4; ++w) s += tot_s[w];
        out[0] = s / (float)B;
    }
}

extern "C" void kernel_launch(void* const* d_in, const int* in_sizes, int n_in,
                              void* d_out, int out_size, void* d_ws, size_t ws_size,
                              hipStream_t stream) {
    const float* ss      = (const float*)d_in[0];
    const float* anchors = (const float*)d_in[1];
    const float* gt      = (const float*)d_in[2];
    float* out  = (float*)d_out;
    float* part = (float*)d_ws;

    const int A = in_sizes[1] / 4;
    const int B = in_sizes[0] / (A * 6);
    const int K = in_sizes[2] / (B * 4);

    const int tileSz = BLOCK * APT;                  // 2048
    const int ntiles = (A + tileSz - 1) / tileSz;    // 59 at A=120000
    const int gx     = ntiles;                       // 236 WGs total

    dim3 grid(gx, B);
    ainno_main<<<grid, BLOCK, 0, stream>>>(ss, anchors, gt, part, A, K, B);
    ainno_final<<<dim3(1), 256, 0, stream>>>(part, out, gx, B);
}